// Round 1
// 533.244 us; speedup vs baseline: 1.1295x; 1.1295x over previous
//
#include <hip/hip_runtime.h>
#include <math.h>

// Problem constants (from reference): B=16384, N=64, D=64
#define BATCH 16384
#define NN 64
#define DD 64
#define RS 65   // stride 65: bank = (n + k) % 32 -> conflict-free column reads (2 lanes/bank)

// 4 waves per block, one batch per block.
// Wave w computes the j-quarter [16w,16w+16) of hidden for all 64 neighbors
// (lane = neighbor). LDS tile shared by 4 waves; acc = 16 VGPRs ->
// __launch_bounds__(256,8) => 64-VGPR cap, 8 blocks/CU, 32 waves/CU.
__global__ __launch_bounds__(256, 8)
void aggregator_kernel(const float* __restrict__ self_v,   // [B,1,64]
                       const float* __restrict__ nv,       // [B,1,64,64]
                       const float* __restrict__ rel,      // [B,1,64,64]
                       const float* __restrict__ ue,       // [B,64]
                       const float* __restrict__ W1,       // [128,64]
                       const float* __restrict__ b1,       // [64]
                       const float* __restrict__ w2,       // [64,1]
                       const float* __restrict__ b2,       // [1]
                       float* __restrict__ out)            // [B,1,128]
{
    const int b = blockIdx.x;
    const int t = threadIdx.x;                              // 0..255
    const int lane = t & 63;
    const int w = __builtin_amdgcn_readfirstlane(t >> 6);   // wave id 0..3 (SGPR)

    __shared__ float rel_s[NN * RS];    // 16640 B
    __shared__ float red_s[4][DD];      // u1 partials, then w2-dot partials
    __shared__ float agg_s[4][DD];      // aggregation partials

    const float* __restrict__ relb = rel + (size_t)b * (NN * DD);

    // ---- stage rel (16 KB) into LDS: coalesced float4 loads, stride-65 rows ----
    #pragma unroll
    for (int i = 0; i < 4; ++i) {
        int idx = i * 256 + t;                 // float4 index within the 64x64 tile
        float4 v = ((const float4*)relb)[idx];
        int n = idx >> 4;                      // row (neighbor)
        int k = (idx & 15) * 4;                // col
        float* p = &rel_s[n * RS + k];         // odd stride: scalar writes (2-way banked = free)
        p[0] = v.x; p[1] = v.y; p[2] = v.z; p[3] = v.w;
    }

    // ---- u1 partials: thread covers j=lane, k in [16w,16w+16) ----
    {
        const float* __restrict__ ueb = ue + (size_t)b * DD + 16 * w;  // wave-uniform -> s_load
        float pu = 0.0f;
        #pragma unroll
        for (int kk = 0; kk < 16; ++kk) {
            pu = fmaf(ueb[kk], W1[(16 * w + kk) * DD + lane], pu);     // W1 coalesced
        }
        red_s[w][lane] = pu;
    }
    __syncthreads();

    // ---- acc init: u1[16w+jj] = b1 + sum of 4 partials (uniform LDS broadcasts) ----
    float acc[16];
    {
        const float* __restrict__ b1q = b1 + 16 * w;
        #pragma unroll
        for (int jj = 0; jj < 16; ++jj) {
            int j = 16 * w + jj;
            acc[jj] = b1q[jj] + red_s[0][j] + red_s[1][j] + red_s[2][j] + red_s[3][j];
        }
    }

    // ---- main loop: h[n=lane][16w+jj] += rel[n][k] * W1b[k][16w+jj] ----
    const float* __restrict__ Wq = W1 + DD * DD + 16 * w;   // rows 64..127, col quarter
    #pragma unroll 4
    for (int k = 0; k < DD; ++k) {
        float x = rel_s[lane * RS + k];                     // bank=(lane+k)&31: conflict-free
        const float* __restrict__ row = Wq + (size_t)k * DD;// wave-uniform -> s_load
        #pragma unroll
        for (int jj = 0; jj < 16; ++jj) acc[jj] = fmaf(x, row[jj], acc[jj]);
    }

    // ---- partial dot with w2 over this j-quarter ----
    {
        const float* __restrict__ w2q = w2 + 16 * w;        // wave-uniform -> s_load
        float pd = 0.0f;
        #pragma unroll
        for (int jj = 0; jj < 16; ++jj) pd = fmaf(fmaxf(acc[jj], 0.0f), w2q[jj], pd);
        __syncthreads();               // all waves done READING u1 partials in red_s
        red_s[w][lane] = pd;
    }
    __syncthreads();

    // ---- decay + softmax over 64 neighbors (redundant per wave; n = lane) ----
    float d = b2[0] + red_s[0][lane] + red_s[1][lane] + red_s[2][lane] + red_s[3][lane];
    float dec = 1.0f / (1.0f + __expf(-d));
    float m = dec;
    #pragma unroll
    for (int off = 32; off > 0; off >>= 1) m = fmaxf(m, __shfl_xor(m, off, 64));
    float e = __expf(dec - m);
    float s = e;
    #pragma unroll
    for (int off = 32; off > 0; off >>= 1) s += __shfl_xor(s, off, 64);
    float wv = e / s;                  // softmax weight for neighbor 'lane'

    // ---- aggregation: wave w covers n in [16w,16w+16), j = lane (coalesced) ----
    const float* __restrict__ nvb = nv + (size_t)b * (NN * DD) + (size_t)(16 * w) * DD + lane;
    float pa = 0.0f;
    #pragma unroll
    for (int i = 0; i < 16; ++i) {
        float wi = __shfl(wv, 16 * w + i, 64);              // uniform lane -> v_readlane
        pa = fmaf(wi, nvb[(size_t)i * DD], pa);             // imm-offset global loads
    }
    agg_s[w][lane] = pa;
    __syncthreads();

    // ---- output: [self | agg] ----
    if (t < 64) {
        out[(size_t)b * (2 * DD) + t] = self_v[(size_t)b * DD + t];
    } else if (t < 128) {
        int j = t - 64;
        out[(size_t)b * (2 * DD) + DD + j] =
            agg_s[0][j] + agg_s[1][j] + agg_s[2][j] + agg_s[3][j];
    }
}

extern "C" void kernel_launch(void* const* d_in, const int* in_sizes, int n_in,
                              void* d_out, int out_size, void* d_ws, size_t ws_size,
                              hipStream_t stream) {
    const float* self_v = (const float*)d_in[0];
    const float* nv     = (const float*)d_in[1];
    const float* rel    = (const float*)d_in[2];
    const float* ue     = (const float*)d_in[3];
    const float* W1     = (const float*)d_in[4];
    const float* b1     = (const float*)d_in[5];
    const float* w2     = (const float*)d_in[6];
    const float* b2     = (const float*)d_in[7];
    float* out = (float*)d_out;

    aggregator_kernel<<<dim3(BATCH), dim3(256), 0, stream>>>(
        self_v, nv, rel, ue, W1, b1, w2, b2, out);
}

// Round 3
// 532.957 us; speedup vs baseline: 1.1301x; 1.0005x over previous
//
#include <hip/hip_runtime.h>
#include <math.h>

// Problem constants (from reference): B=16384, N=64, D=64
#define BATCH 16384
#define NN 64
#define DD 64
#define RS 65   // stride 65: bank = (n + k) % 32 -> 2-way on b32 reads = free (m136)

// 4 waves per block, one batch per block.
// Wave w computes the j-quarter [16w,16w+16) of hidden for all 64 neighbors
// (lane = neighbor). acc = 16 VGPRs + 16 nv-prefetch regs; __launch_bounds__(256,8)
// => 64-VGPR cap, LDS 19.7KB -> 8 blocks/CU = 32 waves/CU (occupancy max).
__global__ __launch_bounds__(256, 8)
void aggregator_kernel(const float* __restrict__ self_v,   // [B,1,64]
                       const float* __restrict__ nv,       // [B,1,64,64]
                       const float* __restrict__ rel,      // [B,1,64,64]
                       const float* __restrict__ ue,       // [B,64]
                       const float* __restrict__ W1,       // [128,64]
                       const float* __restrict__ b1,       // [64]
                       const float* __restrict__ w2,       // [64,1]
                       const float* __restrict__ b2,       // [1]
                       float* __restrict__ out)            // [B,1,128]
{
    const int b = blockIdx.x;
    const int t = threadIdx.x;                              // 0..255
    const int lane = t & 63;
    const int w = __builtin_amdgcn_readfirstlane(t >> 6);   // wave id 0..3 (SGPR)

    __shared__ float rel_s[NN * RS];    // 16640 B
    __shared__ float u1p_s[4][DD];      // u1 k-quarter partials
    __shared__ float pd_s[4][DD];       // w2-dot j-quarter partials
    __shared__ float agg_s[4][DD];      // aggregation n-quarter partials

    const float* __restrict__ relb = rel + (size_t)b * (NN * DD);

    // ---- 1. issue rel loads first (cold HBM, ~900cyc) ----
    float4 r[4];
    #pragma unroll
    for (int i = 0; i < 4; ++i) r[i] = ((const float4*)relb)[i * 256 + t];

    // ---- 2. u1 partial overlaps the rel fill (W1 is hot in L2) ----
    // thread covers j=lane, k in [16w,16w+16)
    {
        const float* __restrict__ ueb = ue + (size_t)b * DD + 16 * w;  // wave-uniform -> s_load
        float pu = 0.0f;
        #pragma unroll
        for (int kk = 0; kk < 16; ++kk) {
            pu = fmaf(ueb[kk], W1[(16 * w + kk) * DD + lane], pu);     // W1 coalesced
        }
        u1p_s[w][lane] = pu;
    }

    // self-vector passthrough: only wave 0 needs it (wave-uniform branch)
    float sv = 0.0f;
    if (w == 0) sv = self_v[(size_t)b * DD + lane];

    // ---- 3. write rel to LDS (vmcnt wait lands here), stride-65 rows ----
    #pragma unroll
    for (int i = 0; i < 4; ++i) {
        int idx = i * 256 + t;                 // float4 index within 64x64 tile
        int n = idx >> 4;                      // row (neighbor)
        int k = (idx & 15) * 4;                // col
        float* p = &rel_s[n * RS + k];         // odd stride: scalar writes (2-way = free)
        p[0] = r[i].x; p[1] = r[i].y; p[2] = r[i].z; p[3] = r[i].w;
    }
    __syncthreads();   // sync1: rel_s + u1p_s ready

    // ---- 4. prefetch nv for the agg phase NOW; consumed ~2500cyc later ----
    // wave w covers n in [16w,16w+16), j = lane (coalesced 256B rows)
    const float* __restrict__ nvb = nv + (size_t)b * (NN * DD) + (size_t)(16 * w) * DD + lane;
    float nvr[16];
    #pragma unroll
    for (int i = 0; i < 16; ++i) nvr[i] = nvb[(size_t)i * DD];

    // ---- 5. acc init: u1[16w+jj] = b1 + sum of 4 partials (uniform broadcasts) ----
    float acc[16];
    #pragma unroll
    for (int jj = 0; jj < 16; ++jj) {
        int j = 16 * w + jj;
        acc[jj] = b1[j] + u1p_s[0][j] + u1p_s[1][j] + u1p_s[2][j] + u1p_s[3][j];
    }

    // ---- 6. main loop: h[n=lane][16w+jj] += rel[n][k] * W1b[k][16w+jj] ----
    const float* __restrict__ Wq = W1 + DD * DD + 16 * w;   // rows 64..127, col quarter
    #pragma unroll 4
    for (int k = 0; k < DD; ++k) {
        float x = rel_s[lane * RS + k];                     // bank=(lane+k)&31: 2-way, free
        const float* __restrict__ row = Wq + (size_t)k * DD;// wave-uniform -> s_load 64B
        #pragma unroll
        for (int jj = 0; jj < 16; ++jj) acc[jj] = fmaf(x, row[jj], acc[jj]);
    }

    // ---- 7. partial dot with w2 over this j-quarter ----
    {
        const float* __restrict__ w2q = w2 + 16 * w;        // wave-uniform -> s_load
        float pd = 0.0f;
        #pragma unroll
        for (int jj = 0; jj < 16; ++jj) pd = fmaf(fmaxf(acc[jj], 0.0f), w2q[jj], pd);
        pd_s[w][lane] = pd;
    }
    __syncthreads();   // sync2: pd partials ready

    // ---- 8. decay + softmax over 64 neighbors (redundant per wave; n = lane) ----
    float d = b2[0] + pd_s[0][lane] + pd_s[1][lane] + pd_s[2][lane] + pd_s[3][lane];
    float dec = 1.0f / (1.0f + __expf(-d));
    float m = dec;
    #pragma unroll
    for (int off = 32; off > 0; off >>= 1) m = fmaxf(m, __shfl_xor(m, off, 64));
    float e = __expf(dec - m);
    float s = e;
    #pragma unroll
    for (int off = 32; off > 0; off >>= 1) s += __shfl_xor(s, off, 64);
    float wv = e / s;                  // softmax weight for neighbor 'lane'

    // ---- 9. aggregation from prefetched registers (no memory on critical path) ----
    float pa = 0.0f;
    #pragma unroll
    for (int i = 0; i < 16; ++i) {
        float wi = __shfl(wv, 16 * w + i, 64);              // uniform lane -> v_readlane
        pa = fmaf(wi, nvr[i], pa);
    }
    agg_s[w][lane] = pa;

    // self half of the output can go out before the last barrier
    if (w == 0) out[(size_t)b * (2 * DD) + lane] = sv;
    __syncthreads();   // sync3: agg partials ready

    if (w == 0) {
        out[(size_t)b * (2 * DD) + DD + lane] =
            agg_s[0][lane] + agg_s[1][lane] + agg_s[2][lane] + agg_s[3][lane];
    }
}

extern "C" void kernel_launch(void* const* d_in, const int* in_sizes, int n_in,
                              void* d_out, int out_size, void* d_ws, size_t ws_size,
                              hipStream_t stream) {
    const float* self_v = (const float*)d_in[0];
    const float* nv     = (const float*)d_in[1];
    const float* rel    = (const float*)d_in[2];
    const float* ue     = (const float*)d_in[3];
    const float* W1     = (const float*)d_in[4];
    const float* b1     = (const float*)d_in[5];
    const float* w2     = (const float*)d_in[6];
    const float* b2     = (const float*)d_in[7];
    float* out = (float*)d_out;

    aggregator_kernel<<<dim3(BATCH), dim3(256), 0, stream>>>(
        self_v, nv, rel, ue, W1, b1, w2, b2, out);
}